// Round 15
// baseline (132.479 us; speedup 1.0000x reference)
//
#include <hip/hip_runtime.h>

// KANLayer via INT8 GEMM, i32 accumulation, per-plane scales (r8 scheme,
// absmax 0.41 verified). r15 = r14 gemm (94us, dedup A, BK=256) + fold
// rewritten with INVERSE mapping: thread = one packed 16B chunk -> stores
// perfectly coalesced (r9-r14's forward fold scattered 4B stores cost ~7us;
// r8 totals exposed it). Inverse verified against forward layout:
//   chunk c = ((g*144+kt)*64+lane), byte b  <->
//   col = g*16+(lane&15), p = kt>>4, i = (kt&15)*64+(lane>>4)*16+b.

#define IN_F   1024
#define OUT_F  1024
#define M_DIM  8192
#define N_DIM  1024
#define KP     9
#define K_DIM  (IN_F * KP)     // 9216  (GEMM K, 9 planes)
#define KA     8192            // dedup A row length (8 planes)
#define NT2    36              // K_DIM / 256 slots
#define NKT    (K_DIM / 64)    // 144 (B packed kt-unit = 64)
#define NBCH   (64 * NKT * 64) // 589824 packed 16B chunks (9 MB)

typedef __attribute__((ext_vector_type(4)))  int   i32x4;
typedef __attribute__((ext_vector_type(4)))  float f32x4;
typedef __attribute__((ext_vector_type(16))) char  char16v;

// quantization constants (r8, verified)
#define SX   (6.0f / 127.0f)
#define ISX  (127.0f / 6.0f)
#define ISL  (16129.0f / 3.0f)
#define TB   (0.7f / 127.0f)
#define ITB  (127.0f / 0.7f)
#define ITL  (16129.0f / 0.35f)
#define ITE  (127.0f / 1.4f)

__device__ __constant__ float SCALES[9] = {
    4.2f / 16129.0f,
    2.1f / 2048383.0f,
    2.1f / 2048383.0f,
    1.4f / 16129.0f,
    0.7f / 16129.0f,
    0.7f / 16129.0f,
    0.7f / 16129.0f,
    0.7f / 16129.0f,
    1.4f / 16129.0f
};

__device__ inline float clampf(float v, float lo, float hi) {
    return fminf(fmaxf(v, lo), hi);
}

// --------------------------------------------------------------------------
// prep: blocks 0..2047 = expand (x -> Aq, 8 dedup planes, r14 verified);
//       blocks 2048..4351 = fold (sw,bw -> Bp packed, inverse mapping,
//       coalesced 16B stores).
// --------------------------------------------------------------------------
__global__ void prep(const float* __restrict__ x,
                     const float* __restrict__ sw, const float* __restrict__ bw,
                     signed char* __restrict__ Aq, signed char* __restrict__ Bp) {
    if (blockIdx.x < 2048) {
        // ---- expand (r14): planes {0:xh, 1:xl, 2..7:hat0..5} ----
        int idx = blockIdx.x * 256 + threadIdx.x;   // m*64 + i16
        int m = idx >> 6, i16 = idx & 63;
        const float4* xp = reinterpret_cast<const float4*>(x + ((size_t)m << 10) + i16 * 16);
        float v[16];
        #pragma unroll
        for (int q = 0; q < 4; ++q) {
            float4 f = xp[q];
            v[4*q] = f.x; v[4*q+1] = f.y; v[4*q+2] = f.z; v[4*q+3] = f.w;
        }
        signed char out[8][16];
        #pragma unroll
        for (int e = 0; e < 16; ++e) {
            float xe = v[e];
            float xh = clampf(rintf(xe * ISX), -127.f, 127.f);
            float xl = xe - xh * SX;
            out[0][e] = (signed char)(int)xh;
            out[1][e] = (signed char)(int)clampf(rintf(xl * ISL), -127.f, 127.f);
            float xc = clampf(xe, -1.f, 1.f);
            #pragma unroll
            for (int j = 0; j < 6; ++j) {
                float t = -1.f + 0.4f * (float)j;
                float h = fmaxf(1.f - fabsf((xc - t) * 2.5f), 0.f);
                out[2 + j][e] = (signed char)(int)rintf(h * 127.f);
            }
        }
        size_t base = (size_t)m * KA + i16 * 16;
        #pragma unroll
        for (int p = 0; p < 8; ++p) {
            char16v pk;
            #pragma unroll
            for (int e = 0; e < 16; ++e) pk[e] = out[p][e];
            *reinterpret_cast<char16v*>(Aq + base + (size_t)p * 1024) = pk;
        }
    } else {
        // ---- fold, inverse mapping: one packed 16B chunk per thread ----
        int f = (blockIdx.x - 2048) * 256 + threadIdx.x;   // chunk id
        int g    = f / (NKT * 64);
        int rem  = f - g * (NKT * 64);
        int kt   = rem >> 6;
        int lane = rem & 63;
        int o    = g * 16 + (lane & 15);
        int p    = kt >> 4;                         // plane 0..8
        int i0   = (kt & 15) * 64 + (lane >> 4) * 16;
        const float* swb = sw + ((size_t)o * 1024 + i0) * 12;
        const float* bwb = bw + (size_t)o * 1024 + i0;

        signed char out[16];
        if (p == 0 || p == 2) {                     // wh (pairs xh / xl)
            #pragma unroll
            for (int e = 0; e < 16; ++e)
                out[e] = (signed char)(int)clampf(rintf(bwb[e] * ITB), -127.f, 127.f);
        } else if (p == 1) {                        // wl residual
            #pragma unroll
            for (int e = 0; e < 16; ++e) {
                float w  = bwb[e];
                float wh = clampf(rintf(w * ITB), -127.f, 127.f);
                out[e] = (signed char)(int)clampf(rintf((w - wh * TB) * ITL), -127.f, 127.f);
            }
        } else if (p == 3) {                        // sum knots 0..3 (end)
            #pragma unroll
            for (int e = 0; e < 16; ++e) {
                float4 a = *reinterpret_cast<const float4*>(swb + e * 12);
                out[e] = (signed char)(int)clampf(rintf((a.x + a.y + a.z + a.w) * ITE), -127.f, 127.f);
            }
        } else if (p == 8) {                        // sum knots 8..11 (end)
            #pragma unroll
            for (int e = 0; e < 16; ++e) {
                float4 c4 = *reinterpret_cast<const float4*>(swb + e * 12 + 8);
                out[e] = (signed char)(int)clampf(rintf((c4.x + c4.y + c4.z + c4.w) * ITE), -127.f, 127.f);
            }
        } else {                                    // p = 4..7 -> knot j = p
            #pragma unroll
            for (int e = 0; e < 16; ++e)
                out[e] = (signed char)(int)clampf(rintf(swb[e * 12 + p] * ITB), -127.f, 127.f);
        }
        char16v pk;
        #pragma unroll
        for (int e = 0; e < 16; ++e) pk[e] = out[e];
        *reinterpret_cast<char16v*>(Bp + (size_t)f * 16) = pk;   // coalesced
    }
}

// --------------------------------------------------------------------------
// i8 GEMM (r14, verified 94us): BK=256 slots, one __syncthreads/slot.
// LDS: As 2 x [128][256B] = 64 KiB, XOR swizzle byte ^= ((row&15)<<4) both
// sides. B: reg-dbuf coalesced 1KB fragment loads from packed panel.
// XCD swizzle (r8): XCD c covers by in [c*8, c*8+8) — A fetched once.
// --------------------------------------------------------------------------
__global__ __launch_bounds__(256, 2) void gemm_q(
        const signed char* __restrict__ Aq,   // [M][8192] i8 dedup row-major
        const signed char* __restrict__ Bp,   // fragment-packed, 9 planes
        float* __restrict__ C) {              // [M][N] f32
    __shared__ __align__(16) signed char As[2][128 * 256];   // 2 x 32 KiB

    const int tid  = threadIdx.x;
    const int wave = tid >> 6;
    const int lane = tid & 63;
    const int wr   = wave >> 1;   // 0..1 (M)
    const int wc   = wave & 1;    // 0..1 (N)

    // r8 XCD swizzle (bijective, nwg = 512)
    const int orig = blockIdx.x;
    const int wg   = (orig & 7) * 64 + (orig >> 3);
    const int bx   = wg & 7;      // N tile (BN=128)
    const int by   = wg >> 3;     // M tile (BM=128), 0..63

    // A staging: inst u covers rows u*16 + (tid>>4), chunk (tid&15)*16 B;
    // source col pre-swizzled (row&15 == tid>>4 for all u)
    const int scolb = ((tid & 15) * 16) ^ ((tid >> 4) << 4);

#define STAGE(BUF, T) do {                                                      \
    int t_ = ((T) < NT2 ? (T) : NT2 - 1);                                       \
    int kb_ = t_ * 256 - (t_ >= 4 ? 1024 : 0);   /* dedup redirect */           \
    _Pragma("unroll")                                                           \
    for (int u = 0; u < 8; ++u) {                                               \
        const signed char* ga_ = Aq + (size_t)(by * 128 + u * 16 + (tid >> 4)) * KA + kb_ + scolb; \
        __builtin_amdgcn_global_load_lds(                                       \
            (const __attribute__((address_space(1))) void*)ga_,                 \
            (__attribute__((address_space(3))) void*)(As[BUF] + u * 4096 + wave * 1024), 16, 0, 0); \
    }                                                                           \
} while (0)

#define LOADB(BF, KT) do {                                                      \
    int kt_ = ((KT) < NKT - 1 ? (KT) : NKT - 2);                                \
    _Pragma("unroll")                                                           \
    for (int n2 = 0; n2 < 4; ++n2)                                              \
        _Pragma("unroll")                                                       \
        for (int kk = 0; kk < 2; ++kk)                                          \
            BF[n2 * 2 + kk] = *reinterpret_cast<const i32x4*>(                  \
                Bp + bwv + ((size_t)n2 * NKT + kt_ + kk) * 1024);               \
} while (0)

#define COMPUTE(CUR, H, BF) do {                                                \
    i32x4 af[8];                                                                \
    _Pragma("unroll")                                                           \
    for (int m2 = 0; m2 < 4; ++m2)                                              \
        _Pragma("unroll")                                                       \
        for (int kk = 0; kk < 2; ++kk) {                                        \
            int row = wr * 64 + m2 * 16 + (lane & 15);                          \
            int off = row * 256 + (((H) * 128 + kk * 64 + (lane >> 4) * 16) ^ ((row & 15) << 4)); \
            af[m2 * 2 + kk] = *reinterpret_cast<const i32x4*>(&As[CUR][off]);   \
        }                                                                       \
    __builtin_amdgcn_s_setprio(1);                                              \
    _Pragma("unroll")                                                           \
    for (int kk = 0; kk < 2; ++kk)                                              \
        _Pragma("unroll")                                                       \
        for (int m2 = 0; m2 < 4; ++m2)                                          \
            _Pragma("unroll")                                                   \
            for (int n2 = 0; n2 < 4; ++n2)                                      \
                acci[m2][n2] = __builtin_amdgcn_mfma_i32_16x16x64_i8(           \
                    af[m2 * 2 + kk], BF[n2 * 2 + kk], acci[m2][n2], 0, 0, 0);   \
    __builtin_amdgcn_s_setprio(0);                                              \
} while (0)

    i32x4 acci[4][4];
    f32x4 accf[4][4];
    #pragma unroll
    for (int m2 = 0; m2 < 4; ++m2)
        #pragma unroll
        for (int n2 = 0; n2 < 4; ++n2) {
            acci[m2][n2] = (i32x4){0, 0, 0, 0};
            accf[m2][n2] = (f32x4){0.f, 0.f, 0.f, 0.f};
        }

    // per-wave B base: groups g0 = bx*8 + wc*4 .. +3
    const size_t bwv = ((size_t)(bx * 8 + wc * 4) * NKT) * 1024 + (size_t)lane * 16;

    i32x4 bfL[8], bfH[8];
    STAGE(0, 0);
    LOADB(bfL, 0);

    #pragma unroll 1
    for (int t = 0; t < NT2; ++t) {
        const int cur = t & 1;
        __syncthreads();               // publishes STAGE(t)
        STAGE(cur ^ 1, t + 1);         // prefetch next slot (clamped at end)
        LOADB(bfH, 4 * t + 2);         // intra-slot half, consumed mid-slot
        COMPUTE(cur, 0, bfL);
        LOADB(bfL, 4 * (t + 1));       // next slot's first half (WAR after use)
        COMPUTE(cur, 1, bfH);
        if ((t & 3) == 3) {            // plane boundary: flush i32 -> f32
            float s = SCALES[t >> 2];
            #pragma unroll
            for (int m2 = 0; m2 < 4; ++m2)
                #pragma unroll
                for (int n2 = 0; n2 < 4; ++n2) {
                    #pragma unroll
                    for (int r = 0; r < 4; ++r)
                        accf[m2][n2][r] += s * (float)acci[m2][n2][r];
                    acci[m2][n2] = (i32x4){0, 0, 0, 0};
                }
        }
    }

    // epilogue: C/D layout col = lane&15, row = (lane>>4)*4 + r (verified)
    #pragma unroll
    for (int m2 = 0; m2 < 4; ++m2)
        #pragma unroll
        for (int n2 = 0; n2 < 4; ++n2) {
            const int row = by * 128 + wr * 64 + m2 * 16 + ((lane >> 4) << 2);
            const int col = bx * 128 + wc * 64 + n2 * 16 + (lane & 15);
            #pragma unroll
            for (int r = 0; r < 4; ++r)
                C[(size_t)(row + r) * N_DIM + col] = accf[m2][n2][r];
        }
#undef STAGE
#undef LOADB
#undef COMPUTE
}

// --------------------------------------------------------------------------
extern "C" void kernel_launch(void* const* d_in, const int* in_sizes, int n_in,
                              void* d_out, int out_size, void* d_ws, size_t ws_size,
                              hipStream_t stream) {
    const float* x  = (const float*)d_in[0];   // (4,2048,1024) f32
    const float* sw = (const float*)d_in[1];   // (1024,1024,12) f32
    const float* bw = (const float*)d_in[2];   // (1024,1024) f32
    float* out = (float*)d_out;                // (4,2048,1024) f32

    signed char* Aq = (signed char*)d_ws;                        // 67.1 MB (dedup)
    signed char* Bp = (signed char*)d_ws + (size_t)M_DIM * KA;   // 9.0 MB packed

    prep<<<2048 + NBCH / 256, 256, 0, stream>>>(x, sw, bw, Aq, Bp);
    gemm_q<<<(M_DIM / 128) * (N_DIM / 128), 256, 0, stream>>>(Aq, Bp, out);
}

// Round 16
// 129.994 us; speedup vs baseline: 1.0191x; 1.0191x over previous
//
#include <hip/hip_runtime.h>

// KANLayer via INT8 GEMM, i32 accumulation, per-plane scales (r8 scheme,
// absmax 0.41 verified). r16 = r14 gemm (94us, dedup A, BK=256, best) +
// fold rewritten AGAIN: thread = (g, q, lane) produces ALL 9 planes of one
// 16-i slice -> sw rows read DENSE and exactly once (r15 streamed sw ~6x),
// stores are nine coalesced-1KB chunk runs per wave (r13/14 scattered 4B).
// Same formulas -> bit-identical Bp -> bit-identical output.

#define IN_F   1024
#define OUT_F  1024
#define M_DIM  8192
#define N_DIM  1024
#define KP     9
#define K_DIM  (IN_F * KP)     // 9216  (GEMM K, 9 planes)
#define KA     8192            // dedup A row length (8 planes)
#define NT2    36              // K_DIM / 256 slots
#define NKT    (K_DIM / 64)    // 144 (B packed kt-unit = 64)

typedef __attribute__((ext_vector_type(4)))  int   i32x4;
typedef __attribute__((ext_vector_type(4)))  float f32x4;
typedef __attribute__((ext_vector_type(16))) char  char16v;

// quantization constants (r8, verified)
#define SX   (6.0f / 127.0f)
#define ISX  (127.0f / 6.0f)
#define ISL  (16129.0f / 3.0f)
#define TB   (0.7f / 127.0f)
#define ITB  (127.0f / 0.7f)
#define ITL  (16129.0f / 0.35f)
#define ITE  (127.0f / 1.4f)

__device__ __constant__ float SCALES[9] = {
    4.2f / 16129.0f,
    2.1f / 2048383.0f,
    2.1f / 2048383.0f,
    1.4f / 16129.0f,
    0.7f / 16129.0f,
    0.7f / 16129.0f,
    0.7f / 16129.0f,
    0.7f / 16129.0f,
    1.4f / 16129.0f
};

__device__ inline float clampf(float v, float lo, float hi) {
    return fminf(fmaxf(v, lo), hi);
}

// --------------------------------------------------------------------------
// prep: blocks 0..2047 = expand (r14 verified: x -> Aq, 8 dedup planes);
//       blocks 2048..2303 = fold (all-9-planes-per-thread):
//   thread f: g = f>>10, q = (f>>6)&15, lane = f&63;
//   reads sw rows (o = g*16+(lane&15), i = q*64+(lane>>4)*16 + e, e<16)
//   dense (768 B once) + bw (64 B once); writes 9 chunks of 16 B at
//   ((g*144 + p*16 + q)*64 + lane)*16 — per-wave 9 x 1KB coalesced.
// --------------------------------------------------------------------------
__global__ void prep(const float* __restrict__ x,
                     const float* __restrict__ sw, const float* __restrict__ bw,
                     signed char* __restrict__ Aq, signed char* __restrict__ Bp) {
    if (blockIdx.x < 2048) {
        // ---- expand (r14): planes {0:xh, 1:xl, 2..7:hat0..5} ----
        int idx = blockIdx.x * 256 + threadIdx.x;   // m*64 + i16
        int m = idx >> 6, i16 = idx & 63;
        const float4* xp = reinterpret_cast<const float4*>(x + ((size_t)m << 10) + i16 * 16);
        float v[16];
        #pragma unroll
        for (int q = 0; q < 4; ++q) {
            float4 f = xp[q];
            v[4*q] = f.x; v[4*q+1] = f.y; v[4*q+2] = f.z; v[4*q+3] = f.w;
        }
        signed char out[8][16];
        #pragma unroll
        for (int e = 0; e < 16; ++e) {
            float xe = v[e];
            float xh = clampf(rintf(xe * ISX), -127.f, 127.f);
            float xl = xe - xh * SX;
            out[0][e] = (signed char)(int)xh;
            out[1][e] = (signed char)(int)clampf(rintf(xl * ISL), -127.f, 127.f);
            float xc = clampf(xe, -1.f, 1.f);
            #pragma unroll
            for (int j = 0; j < 6; ++j) {
                float t = -1.f + 0.4f * (float)j;
                float h = fmaxf(1.f - fabsf((xc - t) * 2.5f), 0.f);
                out[2 + j][e] = (signed char)(int)rintf(h * 127.f);
            }
        }
        size_t base = (size_t)m * KA + i16 * 16;
        #pragma unroll
        for (int p = 0; p < 8; ++p) {
            char16v pk;
            #pragma unroll
            for (int e = 0; e < 16; ++e) pk[e] = out[p][e];
            *reinterpret_cast<char16v*>(Aq + base + (size_t)p * 1024) = pk;
        }
    } else {
        // ---- fold: dense reads, coalesced writes, all 9 planes ----
        int f    = (blockIdx.x - 2048) * 256 + threadIdx.x;   // 0..65535
        int g    = f >> 10;
        int q    = (f >> 6) & 15;
        int lane = f & 63;
        int o    = g * 16 + (lane & 15);
        int i0   = q * 64 + (lane >> 4) * 16;

        signed char out[9][16];
        #pragma unroll
        for (int e = 0; e < 16; ++e) {
            const float* row = sw + ((size_t)o * 1024 + i0 + e) * 12;
            float4 a  = *reinterpret_cast<const float4*>(row);       // knots 0..3
            float4 b  = *reinterpret_cast<const float4*>(row + 4);   // knots 4..7
            float4 c4 = *reinterpret_cast<const float4*>(row + 8);   // knots 8..11
            float w   = bw[(size_t)o * 1024 + i0 + e];
            float wh  = clampf(rintf(w * ITB), -127.f, 127.f);
            float wl  = w - wh * TB;
            out[0][e] = (signed char)(int)wh;
            out[1][e] = (signed char)(int)clampf(rintf(wl * ITL), -127.f, 127.f);
            out[2][e] = (signed char)(int)wh;
            out[3][e] = (signed char)(int)clampf(rintf((a.x + a.y + a.z + a.w) * ITE), -127.f, 127.f);
            out[4][e] = (signed char)(int)clampf(rintf(b.x * ITB), -127.f, 127.f);
            out[5][e] = (signed char)(int)clampf(rintf(b.y * ITB), -127.f, 127.f);
            out[6][e] = (signed char)(int)clampf(rintf(b.z * ITB), -127.f, 127.f);
            out[7][e] = (signed char)(int)clampf(rintf(b.w * ITB), -127.f, 127.f);
            out[8][e] = (signed char)(int)clampf(rintf((c4.x + c4.y + c4.z + c4.w) * ITE), -127.f, 127.f);
        }
        #pragma unroll
        for (int p = 0; p < 9; ++p) {
            char16v pk;
            #pragma unroll
            for (int e = 0; e < 16; ++e) pk[e] = out[p][e];
            size_t chunk = ((size_t)g * NKT + p * 16 + q) * 64 + lane;
            *reinterpret_cast<char16v*>(Bp + chunk * 16) = pk;   // coalesced
        }
    }
}

// --------------------------------------------------------------------------
// i8 GEMM (r14, verified 94us): BK=256 slots, one __syncthreads/slot.
// LDS: As 2 x [128][256B] = 64 KiB, XOR swizzle byte ^= ((row&15)<<4) both
// sides. B: reg-dbuf coalesced 1KB fragment loads from packed panel.
// XCD swizzle (r8): XCD c covers by in [c*8, c*8+8) — A fetched once.
// --------------------------------------------------------------------------
__global__ __launch_bounds__(256, 2) void gemm_q(
        const signed char* __restrict__ Aq,   // [M][8192] i8 dedup row-major
        const signed char* __restrict__ Bp,   // fragment-packed, 9 planes
        float* __restrict__ C) {              // [M][N] f32
    __shared__ __align__(16) signed char As[2][128 * 256];   // 2 x 32 KiB

    const int tid  = threadIdx.x;
    const int wave = tid >> 6;
    const int lane = tid & 63;
    const int wr   = wave >> 1;   // 0..1 (M)
    const int wc   = wave & 1;    // 0..1 (N)

    // r8 XCD swizzle (bijective, nwg = 512)
    const int orig = blockIdx.x;
    const int wg   = (orig & 7) * 64 + (orig >> 3);
    const int bx   = wg & 7;      // N tile (BN=128)
    const int by   = wg >> 3;     // M tile (BM=128), 0..63

    // A staging: inst u covers rows u*16 + (tid>>4), chunk (tid&15)*16 B;
    // source col pre-swizzled (row&15 == tid>>4 for all u)
    const int scolb = ((tid & 15) * 16) ^ ((tid >> 4) << 4);

#define STAGE(BUF, T) do {                                                      \
    int t_ = ((T) < NT2 ? (T) : NT2 - 1);                                       \
    int kb_ = t_ * 256 - (t_ >= 4 ? 1024 : 0);   /* dedup redirect */           \
    _Pragma("unroll")                                                           \
    for (int u = 0; u < 8; ++u) {                                               \
        const signed char* ga_ = Aq + (size_t)(by * 128 + u * 16 + (tid >> 4)) * KA + kb_ + scolb; \
        __builtin_amdgcn_global_load_lds(                                       \
            (const __attribute__((address_space(1))) void*)ga_,                 \
            (__attribute__((address_space(3))) void*)(As[BUF] + u * 4096 + wave * 1024), 16, 0, 0); \
    }                                                                           \
} while (0)

#define LOADB(BF, KT) do {                                                      \
    int kt_ = ((KT) < NKT - 1 ? (KT) : NKT - 2);                                \
    _Pragma("unroll")                                                           \
    for (int n2 = 0; n2 < 4; ++n2)                                              \
        _Pragma("unroll")                                                       \
        for (int kk = 0; kk < 2; ++kk)                                          \
            BF[n2 * 2 + kk] = *reinterpret_cast<const i32x4*>(                  \
                Bp + bwv + ((size_t)n2 * NKT + kt_ + kk) * 1024);               \
} while (0)

#define COMPUTE(CUR, H, BF) do {                                                \
    i32x4 af[8];                                                                \
    _Pragma("unroll")                                                           \
    for (int m2 = 0; m2 < 4; ++m2)                                              \
        _Pragma("unroll")                                                       \
        for (int kk = 0; kk < 2; ++kk) {                                        \
            int row = wr * 64 + m2 * 16 + (lane & 15);                          \
            int off = row * 256 + (((H) * 128 + kk * 64 + (lane >> 4) * 16) ^ ((row & 15) << 4)); \
            af[m2 * 2 + kk] = *reinterpret_cast<const i32x4*>(&As[CUR][off]);   \
        }                                                                       \
    __builtin_amdgcn_s_setprio(1);                                              \
    _Pragma("unroll")                                                           \
    for (int kk = 0; kk < 2; ++kk)                                              \
        _Pragma("unroll")                                                       \
        for (int m2 = 0; m2 < 4; ++m2)                                          \
            _Pragma("unroll")                                                   \
            for (int n2 = 0; n2 < 4; ++n2)                                      \
                acci[m2][n2] = __builtin_amdgcn_mfma_i32_16x16x64_i8(           \
                    af[m2 * 2 + kk], BF[n2 * 2 + kk], acci[m2][n2], 0, 0, 0);   \
    __builtin_amdgcn_s_setprio(0);                                              \
} while (0)

    i32x4 acci[4][4];
    f32x4 accf[4][4];
    #pragma unroll
    for (int m2 = 0; m2 < 4; ++m2)
        #pragma unroll
        for (int n2 = 0; n2 < 4; ++n2) {
            acci[m2][n2] = (i32x4){0, 0, 0, 0};
            accf[m2][n2] = (f32x4){0.f, 0.f, 0.f, 0.f};
        }

    // per-wave B base: groups g0 = bx*8 + wc*4 .. +3
    const size_t bwv = ((size_t)(bx * 8 + wc * 4) * NKT) * 1024 + (size_t)lane * 16;

    i32x4 bfL[8], bfH[8];
    STAGE(0, 0);
    LOADB(bfL, 0);

    #pragma unroll 1
    for (int t = 0; t < NT2; ++t) {
        const int cur = t & 1;
        __syncthreads();               // publishes STAGE(t)
        STAGE(cur ^ 1, t + 1);         // prefetch next slot (clamped at end)
        LOADB(bfH, 4 * t + 2);         // intra-slot half, consumed mid-slot
        COMPUTE(cur, 0, bfL);
        LOADB(bfL, 4 * (t + 1));       // next slot's first half (WAR after use)
        COMPUTE(cur, 1, bfH);
        if ((t & 3) == 3) {            // plane boundary: flush i32 -> f32
            float s = SCALES[t >> 2];
            #pragma unroll
            for (int m2 = 0; m2 < 4; ++m2)
                #pragma unroll
                for (int n2 = 0; n2 < 4; ++n2) {
                    #pragma unroll
                    for (int r = 0; r < 4; ++r)
                        accf[m2][n2][r] += s * (float)acci[m2][n2][r];
                    acci[m2][n2] = (i32x4){0, 0, 0, 0};
                }
        }
    }

    // epilogue: C/D layout col = lane&15, row = (lane>>4)*4 + r (verified)
    #pragma unroll
    for (int m2 = 0; m2 < 4; ++m2)
        #pragma unroll
        for (int n2 = 0; n2 < 4; ++n2) {
            const int row = by * 128 + wr * 64 + m2 * 16 + ((lane >> 4) << 2);
            const int col = bx * 128 + wc * 64 + n2 * 16 + (lane & 15);
            #pragma unroll
            for (int r = 0; r < 4; ++r)
                C[(size_t)(row + r) * N_DIM + col] = accf[m2][n2][r];
        }
#undef STAGE
#undef LOADB
#undef COMPUTE
}

// --------------------------------------------------------------------------
extern "C" void kernel_launch(void* const* d_in, const int* in_sizes, int n_in,
                              void* d_out, int out_size, void* d_ws, size_t ws_size,
                              hipStream_t stream) {
    const float* x  = (const float*)d_in[0];   // (4,2048,1024) f32
    const float* sw = (const float*)d_in[1];   // (1024,1024,12) f32
    const float* bw = (const float*)d_in[2];   // (1024,1024) f32
    float* out = (float*)d_out;                // (4,2048,1024) f32

    signed char* Aq = (signed char*)d_ws;                        // 67.1 MB (dedup)
    signed char* Bp = (signed char*)d_ws + (size_t)M_DIM * KA;   // 9.0 MB packed

    prep<<<2048 + 256, 256, 0, stream>>>(x, sw, bw, Aq, Bp);
    gemm_q<<<(M_DIM / 128) * (N_DIM / 128), 256, 0, stream>>>(Aq, Bp, out);
}